// Round 5
// baseline (167.043 us; speedup 1.0000x reference)
//
#include <hip/hip_runtime.h>
#include <hip/hip_bf16.h>

// Problem constants
#define B_SZ 256
#define SDIM 1024
#define ADIM 512

// khyper tiling: actor blocks = 32 o-tiles x 16 h-groups(8 h each)
#define BKC 128                 // k-chunk
#define NKC (SDIM / BKC)        // 8

typedef __attribute__((ext_vector_type(8))) short bf16x8;
typedef __attribute__((ext_vector_type(4))) float f32x4;

__device__ __forceinline__ unsigned short f2bf(float x) {
  union { float f; unsigned u; } v; v.f = x;
  unsigned r = v.u + 0x7FFFu + ((v.u >> 16) & 1u);   // round-to-nearest-even
  return (unsigned short)(r >> 16);
}

// ---------------- Kernel 1: small MLPs + obs->bf16 + cw2b dot ----------------
__global__ __launch_bounds__(128) void kprep(
    const float* __restrict__ obs,
    const float* __restrict__ task, const int* __restrict__ action,
    const float* __restrict__ we1, const float* __restrict__ be1,
    const float* __restrict__ we2, const float* __restrict__ be2,
    const float* __restrict__ aw1, const float* __restrict__ aw1b,
    const float* __restrict__ ab1, const float* __restrict__ ab1b,
    const float* __restrict__ ab2, const float* __restrict__ ab2b,
    const float* __restrict__ cw1, const float* __restrict__ cw1b,
    const float* __restrict__ cb1, const float* __restrict__ cb1b,
    const float* __restrict__ cb2, const float* __restrict__ cb2b,
    const float* __restrict__ cw2b,
    float* __restrict__ ws_ha, float* __restrict__ ws_hc,
    unsigned short* __restrict__ ws_obs,
    float* __restrict__ out)
{
  const int b = blockIdx.x, t = threadIdx.x;
  __shared__ float s_task[64], s_t1[64], s_z[64], s_hb[128], s_red[128];

  // obs row b -> bf16 into ws_obs; also dot(cw2b, obs[b])
  float dotc = 0.0f;
  {
    const float4* orow = (const float4*)(obs + (size_t)b * SDIM);
    const float4* crow = (const float4*)cw2b;
    ushort4* wrow = (ushort4*)(ws_obs + (size_t)b * SDIM);
#pragma unroll
    for (int i = 0; i < 2; ++i) {
      const int idx = t + i * 128;
      float4 v = orow[idx];
      float4 w = crow[idx];
      dotc += v.x * w.x + v.y * w.y + v.z * w.z + v.w * w.w;
      ushort4 u;
      u.x = f2bf(v.x); u.y = f2bf(v.y); u.z = f2bf(v.z); u.w = f2bf(v.w);
      wrow[idx] = u;
    }
  }

  if (t < 64) s_task[t] = task[b * 64 + t];
  __syncthreads();
  if (t < 64) {
    float a = be1[t];
    for (int e = 0; e < 64; ++e) a += s_task[e] * we1[e * 64 + t];
    s_t1[t] = fmaxf(a, 0.0f);
  }
  __syncthreads();
  if (t < 64) {
    float a = be2[t];
    for (int e = 0; e < 64; ++e) a += s_t1[e] * we2[e * 64 + t];
    s_z[t] = fmaxf(a, 0.0f);
  }
  __syncthreads();
  {
    float a1 = aw1b[t], a2 = ab1b[t], a3 = cw1b[t], a4 = cb1b[t];
    for (int e = 0; e < 64; ++e) {
      const float zv = s_z[e];
      a1 += zv * aw1[e * 128 + t];
      a2 += zv * ab1[e * 128 + t];
      a3 += zv * cw1[e * 128 + t];
      a4 += zv * cb1[e * 128 + t];
    }
    ws_ha[b * 128 + t] = fmaxf(a1, 0.0f);
    s_hb[t] = fmaxf(a2, 0.0f);
    ws_hc[b * 128 + t] = fmaxf(a3, 0.0f);
    s_red[t] = fmaxf(a4, 0.0f) * cb2[t] + dotc;   // bv partial + cw2b.obs partial
  }
  __syncthreads();
  // ba -> staged into d_out logits slots (khyper atomically accumulates on top)
  for (int o = t; o < ADIM; o += 128) {
    float a = ab2b[o];
    for (int h = 0; h < 128; ++h) a += s_hb[h] * ab2[h * ADIM + o];
    out[b * ADIM + o] = a;
  }
  // bv + cw2b.obs reduction
  for (int s = 64; s > 0; s >>= 1) {
    __syncthreads();
    if (t < s) s_red[t] += s_red[t + s];
  }
  if (t == 0) {
    out[131840 + b] = s_red[0] + cb2b[0];      // v partial; critic blocks add rest
    out[131072 + b] = (float)action[b];        // action as float
  }
}

// ---------------- Kernel 2: hypernet GEMM, channel-diverse slab decomposition ----------------
// Actor block (o-tile, h-group of 8): A = aw2[h][o0:o0+16][:] (rows at 4KB stride!),
// B = obs fragments in registers (L2), merge acc[o,b] += ha[b,h]*G_h[o,b] per h.
// Bias blocks: W = aw2b rows, weight 1. Critic blocks: M-rows = cw2 h-rows, hc in epilogue.
__global__ __launch_bounds__(512, 4) void khyper(
    const unsigned short* __restrict__ ws_obs,
    const float* __restrict__ aw2, const float* __restrict__ aw2b,
    const float* __restrict__ cw2,
    const float* __restrict__ ws_ha, const float* __restrict__ ws_hc,
    float* __restrict__ d_out)
{
  __shared__ unsigned short Wl[2][16 * BKC];   // 2 x 4KB bf16 W chunks (swizzled)

  const int tid = threadIdx.x;
  const int blk = blockIdx.x;

  int wtype, o0 = 0, h0 = 0, hcount;
  const float* Wbase;
  size_t hstride = 0;
  if (blk < 512) {                    // actor main
    wtype = 0; o0 = (blk & 31) * 16; h0 = (blk >> 5) * 8; hcount = 8;
    Wbase = aw2 + ((size_t)h0 * ADIM + o0) * SDIM;
    hstride = (size_t)ADIM * SDIM;
  } else if (blk < 544) {             // actor bias (aw2b), weight 1
    wtype = 1; o0 = (blk - 512) * 16; hcount = 1;
    Wbase = aw2b + (size_t)o0 * SDIM;
  } else {                            // critic: M-rows are cw2 h-rows
    wtype = 2; hcount = 1;
    Wbase = cw2 + (size_t)(blk - 544) * 16 * SDIM;
  }
  const int steps = NKC * hcount;     // 64 or 8 (always even)

  // W staging map: thread -> (row, float4-within-chunk)
  const int sr = tid >> 5;            // 0..15
  const int sc = tid & 31;            // 0..31
  const float* wsrc = Wbase + (size_t)sr * SDIM + sc * 4;
  const int wldsb = ((sr * 256 + sc * 8) ^ ((sr & 7) << 4));   // swizzled byte off

  const int lane = tid & 63;
  const int wv = tid >> 6;            // 0..7
  const int lrow = lane & 15;
  const int grp = lane >> 4;          // 0..3

  const int b0 = wv * 32 + lrow;      // wave's two b-frag rows
  const int b1 = wv * 32 + 16 + lrow;

  int ardb[4];                        // A-frag swizzled read offsets per k-step
#pragma unroll
  for (int ks = 0; ks < 4; ++ks)
    ardb[ks] = ((lrow * 256 + ks * 64 + grp * 16) ^ ((lrow & 7) << 4));

  f32x4 acc0 = {0.f, 0.f, 0.f, 0.f}, acc1 = {0.f, 0.f, 0.f, 0.f};
  bf16x8 ob0[4], ob1[4];

  auto LOADW = [&](int t) -> float4 {
    const int kcn = (hcount == 8) ? (t >> 3) : t;
    const int hn  = (hcount == 8) ? (t & 7) : 0;
    return *(const float4*)(wsrc + (size_t)hn * hstride + kcn * BKC);
  };
  auto WRITEW = [&](int buf, float4 v) {
    ushort4 p;
    p.x = f2bf(v.x); p.y = f2bf(v.y); p.z = f2bf(v.z); p.w = f2bf(v.w);
    *(ushort4*)((char*)(&Wl[buf][0]) + wldsb) = p;
  };
  auto PRELOAD = [&](int kc) {
    const unsigned short* ob = ws_obs + kc * BKC + grp * 8;
#pragma unroll
    for (int ks = 0; ks < 4; ++ks) {
      ob0[ks] = *(const bf16x8*)(ob + (size_t)b0 * SDIM + ks * 32);
      ob1[ks] = *(const bf16x8*)(ob + (size_t)b1 * SDIM + ks * 32);
    }
  };
  auto STEP = [&](int buf, int h) {
    const char* base = (const char*)(&Wl[buf][0]);
    f32x4 t0 = {0.f, 0.f, 0.f, 0.f}, t1 = {0.f, 0.f, 0.f, 0.f};
#pragma unroll
    for (int ks = 0; ks < 4; ++ks) {
      bf16x8 af = *(const bf16x8*)(base + ardb[ks]);
      t0 = __builtin_amdgcn_mfma_f32_16x16x32_bf16(af, ob0[ks], t0, 0, 0, 0);
      t1 = __builtin_amdgcn_mfma_f32_16x16x32_bf16(af, ob1[ks], t1, 0, 0, 0);
    }
    if (wtype == 0) {
      const float w0 = ws_ha[(size_t)b0 * 128 + h0 + h];
      const float w1 = ws_ha[(size_t)b1 * 128 + h0 + h];
#pragma unroll
      for (int r = 0; r < 4; ++r) { acc0[r] += w0 * t0[r]; acc1[r] += w1 * t1[r]; }
    } else {
#pragma unroll
      for (int r = 0; r < 4; ++r) { acc0[r] += t0[r]; acc1[r] += t1[r]; }
    }
  };

  // Prologue: chunks 0 and 1 in regs; chunk 0 -> LDS buf0
  float4 sregA = LOADW(0);
  float4 sregB = LOADW(1);
  WRITEW(0, sregA);
  asm volatile("s_waitcnt lgkmcnt(0)" ::: "memory");
  __builtin_amdgcn_s_barrier();

#pragma unroll 1
  for (int s = 0; s < steps; s += 2) {
    // even step s: compute buf0
    const int kcE = (hcount == 8) ? (s >> 3) : s;
    const int hE  = (hcount == 8) ? (s & 7) : 0;
    if (hE == 0) PRELOAD(kcE);
    if (s + 2 < steps) sregA = LOADW(s + 2);
    STEP(0, hE);
    WRITEW(1, sregB);                     // chunk for step s+1
    asm volatile("s_waitcnt lgkmcnt(0)" ::: "memory");
    __builtin_amdgcn_sched_barrier(0);
    __builtin_amdgcn_s_barrier();
    // odd step s+1: compute buf1
    const int kcO = (hcount == 8) ? ((s + 1) >> 3) : (s + 1);
    const int hO  = (hcount == 8) ? ((s + 1) & 7) : 0;
    if (hO == 0 && hcount == 1) PRELOAD(kcO);
    if (s + 3 < steps) sregB = LOADW(s + 3);
    STEP(1, hO);
    if (s + 2 < steps) WRITEW(0, sregA);  // chunk for step s+2
    asm volatile("s_waitcnt lgkmcnt(0)" ::: "memory");
    __builtin_amdgcn_sched_barrier(0);
    __builtin_amdgcn_s_barrier();
  }

  // Epilogue
  if (wtype != 2) {
    const int ob = o0 + grp * 4;
#pragma unroll
    for (int r = 0; r < 4; ++r) {
      atomicAdd(&d_out[(size_t)b0 * ADIM + ob + r], acc0[r]);
      atomicAdd(&d_out[(size_t)b1 * ADIM + ob + r], acc1[r]);
    }
  } else {
    const int hb = (blk - 544) * 16 + grp * 4;
    float v0 = 0.f, v1 = 0.f;
#pragma unroll
    for (int r = 0; r < 4; ++r) {
      v0 += ws_hc[(size_t)b0 * 128 + hb + r] * acc0[r];
      v1 += ws_hc[(size_t)b1 * 128 + hb + r] * acc1[r];
    }
    v0 += __shfl_xor(v0, 16, 64); v0 += __shfl_xor(v0, 32, 64);
    v1 += __shfl_xor(v1, 16, 64); v1 += __shfl_xor(v1, 32, 64);
    if (grp == 0) {
      atomicAdd(&d_out[131840 + b0], v0);
      atomicAdd(&d_out[131840 + b1], v1);
    }
  }
}

// ---------------- Kernel 3: log_softmax / entropy / log_prob ----------------
__global__ __launch_bounds__(256) void kfinal(const int* __restrict__ action,
                                              float* __restrict__ d_out)
{
  const int b = blockIdx.x, t = threadIdx.x;
  const float* lrow = d_out + (size_t)b * ADIM;
  __shared__ float sM[4], sS[4], sT[4];

  const float x0 = lrow[t], x1 = lrow[t + 256];
  float m = fmaxf(x0, x1);
#pragma unroll
  for (int s = 1; s < 64; s <<= 1) m = fmaxf(m, __shfl_xor(m, s, 64));
  const int wv = t >> 6, ln = t & 63;
  if (ln == 0) sM[wv] = m;
  __syncthreads();
  m = fmaxf(fmaxf(sM[0], sM[1]), fmaxf(sM[2], sM[3]));

  const float d0 = x0 - m, d1 = x1 - m;
  const float e0 = expf(d0), e1 = expf(d1);
  float s1 = e0 + e1;
  float s2 = e0 * d0 + e1 * d1;
#pragma unroll
  for (int s = 1; s < 64; s <<= 1) {
    s1 += __shfl_xor(s1, s, 64);
    s2 += __shfl_xor(s2, s, 64);
  }
  if (ln == 0) { sS[wv] = s1; sT[wv] = s2; }
  __syncthreads();
  if (t == 0) {
    const float S = sS[0] + sS[1] + sS[2] + sS[3];
    const float T = sT[0] + sT[1] + sT[2] + sT[3];
    const float lnS = logf(S);
    const int a = action[b];
    d_out[131328 + b] = (lrow[a] - m) - lnS;   // log_prob
    d_out[131584 + b] = lnS - T / S;           // entropy
  }
}

extern "C" void kernel_launch(void* const* d_in, const int* in_sizes, int n_in,
                              void* d_out_v, int out_size, void* d_ws, size_t ws_size,
                              hipStream_t stream) {
  const float* obs   = (const float*)d_in[0];
  const float* task  = (const float*)d_in[1];
  const int*   action= (const int*)  d_in[2];
  const float* we1   = (const float*)d_in[3];
  const float* be1   = (const float*)d_in[4];
  const float* we2   = (const float*)d_in[5];
  const float* be2   = (const float*)d_in[6];
  const float* aw1   = (const float*)d_in[7];
  const float* aw1b  = (const float*)d_in[8];
  const float* aw2   = (const float*)d_in[9];
  const float* aw2b  = (const float*)d_in[10];
  const float* ab1   = (const float*)d_in[11];
  const float* ab1b  = (const float*)d_in[12];
  const float* ab2   = (const float*)d_in[13];
  const float* ab2b  = (const float*)d_in[14];
  const float* cw1   = (const float*)d_in[15];
  const float* cw1b  = (const float*)d_in[16];
  const float* cw2   = (const float*)d_in[17];
  const float* cw2b  = (const float*)d_in[18];
  const float* cb1   = (const float*)d_in[19];
  const float* cb1b  = (const float*)d_in[20];
  const float* cb2   = (const float*)d_in[21];
  const float* cb2b  = (const float*)d_in[22];
  float* out = (float*)d_out_v;
  float* ws_ha = (float*)d_ws;                       // [256][128] f32
  float* ws_hc = ws_ha + 256 * 128;                  // [256][128] f32
  unsigned short* ws_obs = (unsigned short*)(ws_hc + 256 * 128);  // [256][1024] bf16

  kprep<<<256, 128, 0, stream>>>(obs, task, action, we1, be1, we2, be2, aw1, aw1b,
                                 ab1, ab1b, ab2, ab2b, cw1, cw1b, cb1, cb1b,
                                 cb2, cb2b, cw2b, ws_ha, ws_hc, ws_obs, out);
  // 512 actor + 32 bias + 8 critic blocks
  khyper<<<552, 512, 0, stream>>>(ws_obs, aw2, aw2b, cw2, ws_ha, ws_hc, out);
  kfinal<<<256, 256, 0, stream>>>(action, out);
}